// Round 4
// baseline (1096.104 us; speedup 1.0000x reference)
//
#include <hip/hip_runtime.h>

typedef __attribute__((ext_vector_type(8))) short short8;
typedef __attribute__((ext_vector_type(4))) float f32x4;

__device__ __forceinline__ void gload_lds16(const void* g, void* l) {
    __builtin_amdgcn_global_load_lds(
        (const __attribute__((address_space(1))) unsigned*)g,
        (__attribute__((address_space(3))) unsigned*)l, 16, 0, 0);
}
#define MFMA16(a, b, c) __builtin_amdgcn_mfma_f32_16x16x32_bf16((a), (b), (c), 0, 0, 0)

// ---------------------------------------------------------------------------
// Hierarchical grid barrier: 512 blocks, 8 sub-counters (64 arrivals each)
// promote into 1 master. Region layout (u32): [0]=master, [16+s*16]=sub s.
// Co-residency guaranteed by __launch_bounds__(256,2): 2 blocks/CU x 256 CUs.
// ---------------------------------------------------------------------------
#define BAR_STRIDE 144   // u32 per barrier region
__device__ __forceinline__ void gridbar(unsigned* base) {
    __threadfence();
    __syncthreads();
    if (threadIdx.x == 0) {
        unsigned* sub = base + 16 + (blockIdx.x & 7) * 16;
        unsigned prev = atomicAdd(sub, 1u);
        if (prev == 63u) atomicAdd(base, 1u);
        while (__hip_atomic_load(base, __ATOMIC_RELAXED, __HIP_MEMORY_SCOPE_AGENT) < 8u)
            __builtin_amdgcn_s_sleep(2);
    }
    __syncthreads();
    __threadfence();
}

// ---------------------------------------------------------------------------
// fp32 GEMM tile (R1-proven math): BM=32 BN=64 BK=32, 256 threads, 2x4 micro.
// ---------------------------------------------------------------------------
__device__ __forceinline__
void gemm_dev(const float* __restrict__ A, const float* __restrict__ B,
              const float* __restrict__ bias, float* __restrict__ C,
              int N, int K, int m0, int n0, bool relu,
              float* As, float* Bs)
{
    const int tid = threadIdx.x;
    const int tx = tid & 15, ty = tid >> 4;
    float acc[2][4] = {};
    for (int k0 = 0; k0 < K; k0 += 32) {
        {
            int row = tid >> 3, kq = (tid & 7) << 2;
            float4 v = *(const float4*)&A[(long)(m0 + row) * K + k0 + kq];
            As[(kq + 0) * 36 + row] = v.x; As[(kq + 1) * 36 + row] = v.y;
            As[(kq + 2) * 36 + row] = v.z; As[(kq + 3) * 36 + row] = v.w;
        }
#pragma unroll
        for (int q = 0; q < 2; ++q) {
            int f = tid * 2 + q;
            int kk = f >> 4, nn = (f & 15) << 2;
            *(float4*)&Bs[kk * 68 + nn] = *(const float4*)&B[(long)(k0 + kk) * N + n0 + nn];
        }
        __syncthreads();
#pragma unroll
        for (int k = 0; k < 32; ++k) {
            float2 a2 = *(const float2*)&As[k * 36 + ty * 2];
            float4 b4 = *(const float4*)&Bs[k * 68 + tx * 4];
            acc[0][0] += a2.x * b4.x; acc[0][1] += a2.x * b4.y;
            acc[0][2] += a2.x * b4.z; acc[0][3] += a2.x * b4.w;
            acc[1][0] += a2.y * b4.x; acc[1][1] += a2.y * b4.y;
            acc[1][2] += a2.y * b4.z; acc[1][3] += a2.y * b4.w;
        }
        __syncthreads();
    }
#pragma unroll
    for (int i = 0; i < 2; ++i) {
        int m = m0 + ty * 2 + i;
#pragma unroll
        for (int j = 0; j < 4; ++j) {
            int n = n0 + tx * 4 + j;
            float v = acc[i][j];
            if (bias) v += bias[n];
            if (relu) v = fmaxf(v, 0.f);
            C[(long)m * N + n] = v;
        }
    }
}

// ---------------------------------------------------------------------------
// LayerNorm(relu(a+b)) for one row of 256 (R1-proven math).
// ---------------------------------------------------------------------------
__device__ __forceinline__
void ln_dev(const float* __restrict__ a, const float* __restrict__ bsrc,
            const float* __restrict__ g, const float* __restrict__ bb,
            float* __restrict__ o, int row, float* scratch)
{
    const int t = threadIdx.x;
    const long idx = (long)row * 256 + t;
    float x = fmaxf(a[idx] + bsrc[idx], 0.f);
    float s = x, s2 = x * x;
#pragma unroll
    for (int off = 1; off < 64; off <<= 1) {
        s  += __shfl_xor(s,  off, 64);
        s2 += __shfl_xor(s2, off, 64);
    }
    const int wd = t >> 6, lane = t & 63;
    __syncthreads();               // protect scratch reuse across calls
    if (lane == 0) { scratch[wd] = s; scratch[4 + wd] = s2; }
    __syncthreads();
    s  = scratch[0] + scratch[1] + scratch[2] + scratch[3];
    s2 = scratch[4] + scratch[5] + scratch[6] + scratch[7];
    const float mu  = s * (1.f / 256.f);
    const float var = s2 * (1.f / 256.f) - mu * mu;
    o[idx] = (x - mu) * rsqrtf(var + 1e-5f) * g[t] + bb[t];
}

// ---------------------------------------------------------------------------
// Mega dense kernel: encoder + 3 GCN layers + hi/hj + w2 split, one launch.
// 512 blocks x 256 threads, 11 grid barriers.
// ---------------------------------------------------------------------------
__global__ __launch_bounds__(256, 2)
void mega(const float* __restrict__ emb, const float* __restrict__ bpm,
          const float* __restrict__ ew1, const float* __restrict__ eb1,
          const float* __restrict__ ew2, const float* __restrict__ eb2,
          const float* __restrict__ wself, const float* __restrict__ bself,
          const float* __restrict__ wedge, const float* __restrict__ bedge,
          const float* __restrict__ lng, const float* __restrict__ lnb,
          const float* __restrict__ mw1, const float* __restrict__ mw2,
          float* __restrict__ h1, float* __restrict__ h,
          float* __restrict__ sf, float* __restrict__ eg, float* __restrict__ ng,
          float* __restrict__ hi, float* __restrict__ hj,
          short* __restrict__ w2th, short* __restrict__ w2tl,
          unsigned* __restrict__ bars)
{
    __shared__ __align__(16) float As[32 * 36];
    __shared__ __align__(16) float Bs[32 * 68];
    const int blk = blockIdx.x;
    int ib = 0;

    // P0: enc1 (256 tiles) || w2 transpose+split (blocks 256..383)
    if (blk < 256) {
        gemm_dev(emb, ew1, eb1, h1, 512, 640, (blk >> 3) * 32, (blk & 7) * 64, true, As, Bs);
    } else {
        int e = (blk - 256) * 256 + threadIdx.x;
        if (e < 32768) {
            int k = e >> 7, n = e & 127;
            float x = mw2[e];
            unsigned hu = __float_as_uint(x) & 0xFFFF0000u;
            w2th[n * 256 + k] = (short)(hu >> 16);
            w2tl[n * 256 + k] = (short)(__float_as_uint(x - __uint_as_float(hu)) >> 16);
        }
    }
    gridbar(bars + (ib++) * BAR_STRIDE);

    // P1: enc2 (128 tiles)
    if (blk < 128)
        gemm_dev(h1, ew2, eb2, h, 256, 512, (blk >> 2) * 32, (blk & 3) * 64, false, As, Bs);
    gridbar(bars + (ib++) * BAR_STRIDE);

    for (int l = 0; l < 3; ++l) {
        // P2: self (blocks 0..127) + edge (128..255)
        if (blk < 128)
            gemm_dev(h, wself + l * 65536, bself + l * 256, sf, 256, 256,
                     (blk >> 2) * 32, (blk & 3) * 64, false, As, Bs);
        else if (blk < 256) {
            int t = blk - 128;
            gemm_dev(h, wedge + l * 65536, bedge + l * 256, eg, 256, 256,
                     (t >> 2) * 32, (t & 3) * 64, false, As, Bs);
        }
        gridbar(bars + (ib++) * BAR_STRIDE);

        // P3: bmm ng[b] = bp[b] @ eg[b]  (128 tiles)
        if (blk < 128) {
            int bb = blk >> 5, r = blk & 31;
            gemm_dev(bpm + bb * 65536, eg + bb * 65536, nullptr, ng + bb * 65536,
                     256, 256, (r >> 2) * 32, (r & 3) * 64, false, As, Bs);
        }
        gridbar(bars + (ib++) * BAR_STRIDE);

        // P4: LN, 2 rows/block
        ln_dev(sf, ng, lng + l * 256, lnb + l * 256, h, blk * 2, As);
        ln_dev(sf, ng, lng + l * 256, lnb + l * 256, h, blk * 2 + 1, As);
        gridbar(bars + (ib++) * BAR_STRIDE);
    }

    // P5: hi (0..127) + hj (128..255)
    if (blk < 128)
        gemm_dev(h, mw1, nullptr, hi, 256, 256, (blk >> 2) * 32, (blk & 3) * 64, false, As, Bs);
    else if (blk < 256) {
        int t = blk - 128;
        gemm_dev(h, mw1 + 65536, nullptr, hj, 256, 256, (t >> 2) * 32, (t & 3) * 64, false, As, Bs);
    }
}

// ---------------------------------------------------------------------------
// Pairwise scorer v2: in-register P build, MFMA 3-pass trunc-split.
// Block: 128 pairs (2 i x 64 j) x N=128, 4 waves (2 pair-halves x 2 N-halves).
// hjs staged via global_load_lds with pre-swizzled source (conflict-free read).
// One barrier per k-tile.
// ---------------------------------------------------------------------------
__global__ __launch_bounds__(256, 3)
void pairwise2(const float* __restrict__ hia, const float* __restrict__ hja,
               const float* __restrict__ bpm,
               const float* __restrict__ c, const float* __restrict__ b1,
               const short* __restrict__ w2th, const short* __restrict__ w2tl,
               const float* __restrict__ b2, const float* __restrict__ w3,
               const float* __restrict__ b3, float* __restrict__ out)
{
    const int b = blockIdx.z, ib0 = blockIdx.y * 2, j0 = blockIdx.x * 64;
    const int tid = threadIdx.x, l = tid & 63, wid = tid >> 6;
    const int wm0 = (wid & 1) * 64, wn0 = (wid >> 1) * 64;
    const int g = l >> 4, ln = l & 15;
    const int ii = wid & 1;

    __shared__ __align__(16) float hjs[2][64 * 32];   // swizzled content
    __shared__ __align__(16) float hib[2][256];       // hi row + b1
    __shared__ __align__(16) float csv[256];
    __shared__ float red[128][2];

    {   // persistent staging: hib = hi + b1 (full K), csv = c
        int i2 = tid >> 7, kk = (tid & 127) * 2;
        float2 hv = *(const float2*)&hia[((long)(b * 256 + ib0 + i2)) * 256 + kk];
        float2 bv = *(const float2*)&b1[kk];
        hib[i2][kk] = hv.x + bv.x; hib[i2][kk + 1] = hv.y + bv.y;
        if (tid < 64) *(float4*)&csv[tid * 4] = *(const float4*)&c[tid * 4];
    }
    float bw[4];
#pragma unroll
    for (int mf = 0; mf < 4; ++mf)
        bw[mf] = bpm[((long)(b * 256 + ib0 + ii)) * 256 + j0 + mf * 16 + ln];

    {   // stage hjs[0] (k-tile 0), pre-swizzled source: q_src = q ^ (row&7)
        int row = tid >> 3, q = tid & 7;
        gload_lds16(&hja[((long)(b * 256 + j0 + row)) * 256 + (q ^ (row & 7)) * 4],
                    (char*)&hjs[0][0] + tid * 16);
        int row2 = 32 + row;
        gload_lds16(&hja[((long)(b * 256 + j0 + row2)) * 256 + (q ^ (row2 & 7)) * 4],
                    (char*)&hjs[0][0] + 4096 + tid * 16);
    }
    __syncthreads();

    f32x4 acc[4][4] = {};

    for (int kt = 0; kt < 8; ++kt) {
        const int cur = kt & 1;
        if (kt < 7) {   // stage hjs(t+1) into other buffer
            int row = tid >> 3, q = tid & 7;
            gload_lds16(&hja[((long)(b * 256 + j0 + row)) * 256 + (kt + 1) * 32
                             + (q ^ (row & 7)) * 4],
                        (char*)&hjs[cur ^ 1][0] + tid * 16);
            int row2 = 32 + row;
            gload_lds16(&hja[((long)(b * 256 + j0 + row2)) * 256 + (kt + 1) * 32
                             + (q ^ (row2 & 7)) * 4],
                        (char*)&hjs[cur ^ 1][0] + 4096 + tid * 16);
        }
        // B fragments (L2-hot small matrix)
        short8 bh[4], bl[4];
#pragma unroll
        for (int nf = 0; nf < 4; ++nf) {
            int col = wn0 + nf * 16 + ln;
            long bo = (long)col * 256 + kt * 32 + g * 8;
            bh[nf] = *(const short8*)(w2th + bo);
            bl[nf] = *(const short8*)(w2tl + bo);
        }
        // broadcast k-slices (no conflict: 16 lanes same address)
        float hv8[8], cv8[8];
        *(float4*)&hv8[0] = *(const float4*)&hib[ii][kt * 32 + g * 8];
        *(float4*)&hv8[4] = *(const float4*)&hib[ii][kt * 32 + g * 8 + 4];
        *(float4*)&cv8[0] = *(const float4*)&csv[kt * 32 + g * 8];
        *(float4*)&cv8[4] = *(const float4*)&csv[kt * 32 + g * 8 + 4];

#pragma unroll
        for (int mf = 0; mf < 4; ++mf) {
            const int jj = mf * 16 + ln;
            const int rowbase = jj * 128;
            const int sw = (jj & 7) << 4;
            float hjv[8];
            *(float4*)&hjv[0] = *(const float4*)((const char*)&hjs[cur][0]
                                                 + rowbase + ((g * 32) ^ sw));
            *(float4*)&hjv[4] = *(const float4*)((const char*)&hjs[cur][0]
                                                 + rowbase + ((g * 32 + 16) ^ sw));
            unsigned ph[4], pl[4];
#pragma unroll
            for (int e = 0; e < 4; ++e) {
                float x0 = fmaxf(fmaf(bw[mf], cv8[2 * e],     hv8[2 * e])     + hjv[2 * e],     0.f);
                float x1 = fmaxf(fmaf(bw[mf], cv8[2 * e + 1], hv8[2 * e + 1]) + hjv[2 * e + 1], 0.f);
                unsigned u0 = __float_as_uint(x0), u1 = __float_as_uint(x1);
                unsigned h0 = u0 & 0xFFFF0000u, h1 = u1 & 0xFFFF0000u;
                ph[e] = (h0 >> 16) | h1;
                unsigned l0 = __float_as_uint(x0 - __uint_as_float(h0));
                unsigned l1 = __float_as_uint(x1 - __uint_as_float(h1));
                pl[e] = (l0 >> 16) | (l1 & 0xFFFF0000u);
            }
            union { unsigned u[4]; short8 s; } ua, ul;
            ua.u[0] = ph[0]; ua.u[1] = ph[1]; ua.u[2] = ph[2]; ua.u[3] = ph[3];
            ul.u[0] = pl[0]; ul.u[1] = pl[1]; ul.u[2] = pl[2]; ul.u[3] = pl[3];
#pragma unroll
            for (int nf = 0; nf < 4; ++nf) {
                acc[mf][nf] = MFMA16(ua.s, bh[nf], acc[mf][nf]);
                acc[mf][nf] = MFMA16(ua.s, bl[nf], acc[mf][nf]);
                acc[mf][nf] = MFMA16(ul.s, bh[nf], acc[mf][nf]);
            }
        }
        __syncthreads();   // gload_lds(t+1) drained; hjs[cur] reads done
    }

    // epilogue: relu(+b2) dot w3, 16-lane shfl reduce, cross-wave via LDS
    float b2v[4], w3v[4];
#pragma unroll
    for (int nf = 0; nf < 4; ++nf) {
        int col = wn0 + nf * 16 + ln;
        b2v[nf] = b2[col];
        w3v[nf] = w3[col];
    }
#pragma unroll
    for (int mf = 0; mf < 4; ++mf) {
#pragma unroll
        for (int r = 0; r < 4; ++r) {
            float s = 0.f;
#pragma unroll
            for (int nf = 0; nf < 4; ++nf)
                s += fmaxf(acc[mf][nf][r] + b2v[nf], 0.f) * w3v[nf];
            s += __shfl_xor(s, 1, 64);
            s += __shfl_xor(s, 2, 64);
            s += __shfl_xor(s, 4, 64);
            s += __shfl_xor(s, 8, 64);
            if (ln == 0)
                red[wm0 + mf * 16 + g * 4 + r][wid >> 1] = s;
        }
    }
    __syncthreads();
    if (tid < 128) {
        int i = ib0 + (tid >> 6), j = j0 + (tid & 63);
        out[((long)(b * 256 + i)) * 256 + j] = red[tid][0] + red[tid][1] + b3[0];
    }
}

// ---------------------------------------------------------------------------
extern "C" void kernel_launch(void* const* d_in, const int* in_sizes, int n_in,
                              void* d_out, int out_size, void* d_ws, size_t ws_size,
                              hipStream_t stream)
{
    const float* emb   = (const float*)d_in[0];
    const float* bpm   = (const float*)d_in[1];
    const float* ew1   = (const float*)d_in[3];
    const float* eb1   = (const float*)d_in[4];
    const float* ew2   = (const float*)d_in[5];
    const float* eb2   = (const float*)d_in[6];
    const float* wself = (const float*)d_in[7];
    const float* bself = (const float*)d_in[8];
    const float* wedge = (const float*)d_in[9];
    const float* bedge = (const float*)d_in[10];
    const float* lng   = (const float*)d_in[11];
    const float* lnb   = (const float*)d_in[12];
    const float* mw1   = (const float*)d_in[13];
    const float* mb1   = (const float*)d_in[14];
    const float* mw2   = (const float*)d_in[15];
    const float* mb2   = (const float*)d_in[16];
    const float* mw3   = (const float*)d_in[17];
    const float* mb3   = (const float*)d_in[18];
    float* out = (float*)d_out;

    float* ws = (float*)d_ws;
    float* h1 = ws;               // 524288
    float* h  = h1 + 524288;      // 262144
    float* sf = h  + 262144;      // 262144
    float* eg = sf + 262144;      // 262144
    float* ng = eg + 262144;      // 262144
    float* hi = ng + 262144;      // 262144
    float* hj = hi + 262144;      // 262144
    short* w2th = (short*)(hj + 262144);     // 32768 shorts
    short* w2tl = w2th + 32768;              // 32768 shorts
    unsigned* bars = (unsigned*)(w2tl + 32768);  // 11 * 144 u32

    hipMemsetAsync(bars, 0, 11 * BAR_STRIDE * sizeof(unsigned), stream);

    mega<<<dim3(512), dim3(256), 0, stream>>>(
        emb, bpm, ew1, eb1, ew2, eb2, wself, bself, wedge, bedge,
        lng, lnb, mw1, mw2, h1, h, sf, eg, ng, hi, hj, w2th, w2tl, bars);

    pairwise2<<<dim3(4, 128, 4), dim3(256), 0, stream>>>(
        hi, hj, bpm, mw1 + 131072, mb1, w2th, w2tl, mb2, mw3, mb3, out);
}

// Round 5
// 315.590 us; speedup vs baseline: 3.4732x; 3.4732x over previous
//
#include <hip/hip_runtime.h>

typedef __attribute__((ext_vector_type(8))) short short8;
typedef __attribute__((ext_vector_type(4))) float f32x4;

__device__ __forceinline__ void gload_lds16(const void* g, void* l) {
    __builtin_amdgcn_global_load_lds(
        (const __attribute__((address_space(1))) unsigned*)g,
        (__attribute__((address_space(3))) unsigned*)l, 16, 0, 0);
}
#define MFMA16(a, b, c) __builtin_amdgcn_mfma_f32_16x16x32_bf16((a), (b), (c), 0, 0, 0)

// ---------------------------------------------------------------------------
// w2 [256][128] -> transposed bf16 hi/lo split [128][256]
// ---------------------------------------------------------------------------
__global__ __launch_bounds__(256)
void splitw2(const float* __restrict__ w2, short* __restrict__ w2th,
             short* __restrict__ w2tl)
{
    int e = blockIdx.x * 256 + threadIdx.x;   // 0..32767
    int k = e >> 7, n = e & 127;
    float x = w2[e];
    unsigned hu = __float_as_uint(x) & 0xFFFF0000u;
    w2th[n * 256 + k] = (short)(hu >> 16);
    w2tl[n * 256 + k] = (short)(__float_as_uint(x - __uint_as_float(hu)) >> 16);
}

// ---------------------------------------------------------------------------
// fp32 GEMM (R2-proven core): BM=32 BN=64 BK=32, 256 thr, 2x4 microtile.
// Dual-B via nxHalf (shares A). Optional LN-on-A-load:
//   A'[m,k] = (A[m,k]-mu[m])*rs[m]*lg[k] + lb[k], stats from ps[4][1024][2].
// ---------------------------------------------------------------------------
template<bool RELU, bool LNA>
__global__ __launch_bounds__(256)
void gemm_f32(const float* __restrict__ A,
              const float* __restrict__ B0, const float* __restrict__ bias0,
              float* __restrict__ C0,
              const float* __restrict__ B1, const float* __restrict__ bias1,
              float* __restrict__ C1,
              const float* __restrict__ ps, const float* __restrict__ lg,
              const float* __restrict__ lb,
              int M, int N, int K, int nxHalf)
{
    int bx = blockIdx.x;
    const float* B = B0; const float* bias = bias0; float* C = C0;
    if (nxHalf && bx >= nxHalf) { bx -= nxHalf; B = B1; bias = bias1; C = C1; }
    const int m0 = blockIdx.y * 32, n0 = bx * 64;
    const int tid = threadIdx.x;
    const int tx = tid & 15, ty = tid >> 4;

    __shared__ __align__(16) float As[32 * 36];
    __shared__ __align__(16) float Bs[32 * 68];
    __shared__ float mus[32], rss[32];

    if (LNA) {
        if (tid < 32) {
            int m = m0 + tid;
            float s  = ps[m * 2]            + ps[2048 + m * 2]
                     + ps[4096 + m * 2]     + ps[6144 + m * 2];
            float s2 = ps[m * 2 + 1]        + ps[2048 + m * 2 + 1]
                     + ps[4096 + m * 2 + 1] + ps[6144 + m * 2 + 1];
            float mu  = s * (1.f / 256.f);
            float var = s2 * (1.f / 256.f) - mu * mu;
            mus[tid] = mu;
            rss[tid] = rsqrtf(var + 1e-5f);
        }
        __syncthreads();
    }

    float acc[2][4] = {};
    for (int k0 = 0; k0 < K; k0 += 32) {
        {
            int row = tid >> 3, kq = (tid & 7) << 2;
            float4 v = *(const float4*)&A[(long)(m0 + row) * K + k0 + kq];
            if (LNA) {
                float4 gv = *(const float4*)&lg[k0 + kq];
                float4 bv = *(const float4*)&lb[k0 + kq];
                float mu = mus[row], rs = rss[row];
                v.x = (v.x - mu) * rs * gv.x + bv.x;
                v.y = (v.y - mu) * rs * gv.y + bv.y;
                v.z = (v.z - mu) * rs * gv.z + bv.z;
                v.w = (v.w - mu) * rs * gv.w + bv.w;
            }
            As[(kq + 0) * 36 + row] = v.x; As[(kq + 1) * 36 + row] = v.y;
            As[(kq + 2) * 36 + row] = v.z; As[(kq + 3) * 36 + row] = v.w;
        }
#pragma unroll
        for (int q = 0; q < 2; ++q) {
            int f = tid * 2 + q;
            int kk = f >> 4, nn = (f & 15) << 2;
            *(float4*)&Bs[kk * 68 + nn] = *(const float4*)&B[(long)(k0 + kk) * N + n0 + nn];
        }
        __syncthreads();
#pragma unroll
        for (int k = 0; k < 32; ++k) {
            float2 a2 = *(const float2*)&As[k * 36 + ty * 2];
            float4 b4 = *(const float4*)&Bs[k * 68 + tx * 4];
            acc[0][0] += a2.x * b4.x; acc[0][1] += a2.x * b4.y;
            acc[0][2] += a2.x * b4.z; acc[0][3] += a2.x * b4.w;
            acc[1][0] += a2.y * b4.x; acc[1][1] += a2.y * b4.y;
            acc[1][2] += a2.y * b4.z; acc[1][3] += a2.y * b4.w;
        }
        __syncthreads();
    }

#pragma unroll
    for (int i = 0; i < 2; ++i) {
        int m = m0 + ty * 2 + i;
#pragma unroll
        for (int j = 0; j < 4; ++j) {
            int n = n0 + tx * 4 + j;
            float v = acc[i][j];
            if (bias) v += bias[n];
            if (RELU) v = fmaxf(v, 0.f);
            C[(long)m * N + n] = v;
        }
    }
}

// ---------------------------------------------------------------------------
// bmm + fused x = relu(sf + bp@eg) + per-row partial LN stats (no atomics).
// Grid (4 n-tiles, 8 m-tiles, 4 batch). ps layout: [jb][1024][2].
// ---------------------------------------------------------------------------
__global__ __launch_bounds__(256)
void bmm_fuse(const float* __restrict__ bp, const float* __restrict__ eg,
              const float* __restrict__ sf, float* __restrict__ x,
              float* __restrict__ ps)
{
    const int b = blockIdx.z, jb = blockIdx.x;
    const int m0 = blockIdx.y * 32, n0 = jb * 64;
    const float* A = bp + b * 65536;
    const float* B = eg + b * 65536;
    const int tid = threadIdx.x;
    const int tx = tid & 15, ty = tid >> 4;

    __shared__ __align__(16) float As[32 * 36];
    __shared__ __align__(16) float Bs[32 * 68];

    float acc[2][4] = {};
    for (int k0 = 0; k0 < 256; k0 += 32) {
        {
            int row = tid >> 3, kq = (tid & 7) << 2;
            float4 v = *(const float4*)&A[(long)(m0 + row) * 256 + k0 + kq];
            As[(kq + 0) * 36 + row] = v.x; As[(kq + 1) * 36 + row] = v.y;
            As[(kq + 2) * 36 + row] = v.z; As[(kq + 3) * 36 + row] = v.w;
        }
#pragma unroll
        for (int q = 0; q < 2; ++q) {
            int f = tid * 2 + q;
            int kk = f >> 4, nn = (f & 15) << 2;
            *(float4*)&Bs[kk * 68 + nn] = *(const float4*)&B[(long)(k0 + kk) * 256 + n0 + nn];
        }
        __syncthreads();
#pragma unroll
        for (int k = 0; k < 32; ++k) {
            float2 a2 = *(const float2*)&As[k * 36 + ty * 2];
            float4 b4 = *(const float4*)&Bs[k * 68 + tx * 4];
            acc[0][0] += a2.x * b4.x; acc[0][1] += a2.x * b4.y;
            acc[0][2] += a2.x * b4.z; acc[0][3] += a2.x * b4.w;
            acc[1][0] += a2.y * b4.x; acc[1][1] += a2.y * b4.y;
            acc[1][2] += a2.y * b4.z; acc[1][3] += a2.y * b4.w;
        }
        __syncthreads();
    }

#pragma unroll
    for (int i = 0; i < 2; ++i) {
        int gm = b * 256 + m0 + ty * 2 + i;
        float s = 0.f, s2 = 0.f;
#pragma unroll
        for (int j = 0; j < 4; ++j) {
            int n = n0 + tx * 4 + j;
            float v = fmaxf(acc[i][j] + sf[(long)gm * 256 + n], 0.f);
            x[(long)gm * 256 + n] = v;
            s += v; s2 += v * v;
        }
        s  += __shfl_xor(s, 1, 64);  s2 += __shfl_xor(s2, 1, 64);
        s  += __shfl_xor(s, 2, 64);  s2 += __shfl_xor(s2, 2, 64);
        s  += __shfl_xor(s, 4, 64);  s2 += __shfl_xor(s2, 4, 64);
        s  += __shfl_xor(s, 8, 64);  s2 += __shfl_xor(s2, 8, 64);
        if (tx == 0) {
            ps[jb * 2048 + gm * 2]     = s;
            ps[jb * 2048 + gm * 2 + 1] = s2;
        }
    }
}

// ---------------------------------------------------------------------------
// Pairwise scorer v3: LDS P build (shared, double-buffered), MFMA 3-pass,
// ONE barrier per k-tile, swizzled hjs staging via global_load_lds.
// Block: 128 pairs (2 i x 64 j) x N=128, 4 waves (2 pair-halves x 2 N-halves).
// ---------------------------------------------------------------------------
#define STAGE_HJ(T, BUF)                                                        \
    {                                                                           \
        int row = tid >> 3, q = tid & 7;                                        \
        gload_lds16(&hja[((long)(b * 256 + j0 + row)) * 256 + (T) * 32          \
                         + (q ^ (row & 7)) * 4],                                \
                    (char*)&hjs[BUF][0] + tid * 16);                            \
        int row2 = row + 32;                                                    \
        gload_lds16(&hja[((long)(b * 256 + j0 + row2)) * 256 + (T) * 32         \
                         + (q ^ (row2 & 7)) * 4],                               \
                    (char*)&hjs[BUF][0] + 4096 + tid * 16);                     \
    }

#define BUILD_P(KT, BUF)                                                        \
    {                                                                           \
        const int p = tid >> 1, kb = (tid & 1) << 4;                            \
        const int ii = p >> 6, jj = p & 63;                                     \
        const float bw = bpv[p];                                                \
        const int swz = (p & 7) << 4;                                           \
        char* ph = (char*)&Ph[BUF][0];                                          \
        char* pl = (char*)&Pl[BUF][0];                                          \
        const char* hbase = (const char*)&hjs[BUF][0] + jj * 128;               \
        _Pragma("unroll")                                                       \
        for (int q = 0; q < 4; ++q) {                                           \
            int kk = kb + q * 4;                                                \
            float4 hv = *(const float4*)(hbase + ((((kk >> 2) ^ (jj & 7))) << 4)); \
            float4 iv = *(const float4*)&hib[ii][(KT) * 32 + kk];               \
            float4 cv = *(const float4*)&csv[(KT) * 32 + kk];                   \
            float x0 = fmaxf(iv.x + hv.x + bw * cv.x, 0.f);                     \
            float x1 = fmaxf(iv.y + hv.y + bw * cv.y, 0.f);                     \
            float x2 = fmaxf(iv.z + hv.z + bw * cv.z, 0.f);                     \
            float x3 = fmaxf(iv.w + hv.w + bw * cv.w, 0.f);                     \
            unsigned h0 = __float_as_uint(x0) & 0xFFFF0000u;                    \
            unsigned h1 = __float_as_uint(x1) & 0xFFFF0000u;                    \
            unsigned h2 = __float_as_uint(x2) & 0xFFFF0000u;                    \
            unsigned h3 = __float_as_uint(x3) & 0xFFFF0000u;                    \
            unsigned l0 = __float_as_uint(x0 - __uint_as_float(h0));            \
            unsigned l1 = __float_as_uint(x1 - __uint_as_float(h1));            \
            unsigned l2 = __float_as_uint(x2 - __uint_as_float(h2));            \
            unsigned l3 = __float_as_uint(x3 - __uint_as_float(h3));            \
            int bb2 = p * 64 + kk * 2;                                          \
            *(unsigned*)(ph + ((bb2    ) ^ swz)) = (h0 >> 16) | h1;             \
            *(unsigned*)(ph + ((bb2 + 4) ^ swz)) = (h2 >> 16) | h3;             \
            *(unsigned*)(pl + ((bb2    ) ^ swz)) = (l0 >> 16) | (l1 & 0xFFFF0000u); \
            *(unsigned*)(pl + ((bb2 + 4) ^ swz)) = (l2 >> 16) | (l3 & 0xFFFF0000u); \
        }                                                                       \
    }

__global__ __launch_bounds__(256, 3)
void pairwise3(const float* __restrict__ hia, const float* __restrict__ hja,
               const float* __restrict__ bpm,
               const float* __restrict__ c, const float* __restrict__ b1,
               const short* __restrict__ w2th, const short* __restrict__ w2tl,
               const float* __restrict__ b2, const float* __restrict__ w3,
               const float* __restrict__ b3, float* __restrict__ out)
{
    const int b = blockIdx.z, ib0 = blockIdx.y * 2, j0 = blockIdx.x * 64;
    const int tid = threadIdx.x, l = tid & 63, wid = tid >> 6;
    const int wm0 = (wid & 1) * 64, wn0 = (wid >> 1) * 64;
    const int g = l >> 4, ln = l & 15;

    __shared__ __align__(16) short Ph[2][4096];   // [buf][row*32+k], swizzled
    __shared__ __align__(16) short Pl[2][4096];
    __shared__ __align__(16) float hjs[2][2048];  // [buf][row*32], src-swizzled
    __shared__ __align__(16) float hib[2][256];   // hi row + b1
    __shared__ __align__(16) float csv[256];
    __shared__ float bpv[128];
    __shared__ float red[128][2];

    if (tid < 128)
        bpv[tid] = bpm[((long)(b * 256 + ib0 + (tid >> 6))) * 256 + j0 + (tid & 63)];
    {
        int i2 = tid >> 7, kk = (tid & 127) * 2;
        float2 hv = *(const float2*)&hia[((long)(b * 256 + ib0 + i2)) * 256 + kk];
        float2 bv = *(const float2*)&b1[kk];
        hib[i2][kk] = hv.x + bv.x; hib[i2][kk + 1] = hv.y + bv.y;
    }
    if (tid < 64) *(float4*)&csv[tid * 4] = *(const float4*)&c[tid * 4];

    STAGE_HJ(0, 0);
    __syncthreads();
    STAGE_HJ(1, 1);
    BUILD_P(0, 0);
    __syncthreads();

    f32x4 acc[4][4] = {};

#pragma unroll
    for (int kt = 0; kt < 8; ++kt) {
        const int cur = kt & 1;
        // B(t) fragments (global, L2-hot) — issued early, consumed at MFMA
        short8 bh[4], bl[4];
#pragma unroll
        for (int nf = 0; nf < 4; ++nf) {
            int col = wn0 + nf * 16 + ln;
            long bo = (long)col * 256 + kt * 32 + g * 8;
            bh[nf] = *(const short8*)(w2th + bo);
            bl[nf] = *(const short8*)(w2tl + bo);
        }
        // A(t) fragments from P[cur] (built last iteration)
        short8 ah[4], al[4];
#pragma unroll
        for (int mf = 0; mf < 4; ++mf) {
            int row = wm0 + mf * 16 + ln;
            int off = (row * 64 + g * 16) ^ ((row & 7) << 4);
            ah[mf] = *(const short8*)((const char*)&Ph[cur][0] + off);
            al[mf] = *(const short8*)((const char*)&Pl[cur][0] + off);
        }
        // stage hjs(t+2) into hjs[cur] (drained at this iteration's barrier)
        if (kt < 6) STAGE_HJ(kt + 2, cur);
        // build P(t+1) into buf cur^1 (reads hjs[cur^1], staged 2 iters ago)
        if (kt < 7) BUILD_P(kt + 1, cur ^ 1);
        // MFMA(t): 3-pass hi/lo split
#pragma unroll
        for (int mf = 0; mf < 4; ++mf)
#pragma unroll
            for (int nf = 0; nf < 4; ++nf) {
                acc[mf][nf] = MFMA16(ah[mf], bh[nf], acc[mf][nf]);
                acc[mf][nf] = MFMA16(ah[mf], bl[nf], acc[mf][nf]);
                acc[mf][nf] = MFMA16(al[mf], bh[nf], acc[mf][nf]);
            }
        __syncthreads();
    }

    // epilogue: relu(+b2) dot w3, 16-lane shfl reduce, cross-wave via LDS
    float b2v[4], w3v[4];
#pragma unroll
    for (int nf = 0; nf < 4; ++nf) {
        int col = wn0 + nf * 16 + ln;
        b2v[nf] = b2[col];
        w3v[nf] = w3[col];
    }
#pragma unroll
    for (int mf = 0; mf < 4; ++mf) {
#pragma unroll
        for (int r = 0; r < 4; ++r) {
            float s = 0.f;
#pragma unroll
            for (int nf = 0; nf < 4; ++nf)
                s += fmaxf(acc[mf][nf][r] + b2v[nf], 0.f) * w3v[nf];
            s += __shfl_xor(s, 1, 64);
            s += __shfl_xor(s, 2, 64);
            s += __shfl_xor(s, 4, 64);
            s += __shfl_xor(s, 8, 64);
            if (ln == 0)
                red[wm0 + mf * 16 + g * 4 + r][wid >> 1] = s;
        }
    }
    __syncthreads();
    if (tid < 128) {
        int i = ib0 + (tid >> 6), j = j0 + (tid & 63);
        out[((long)(b * 256 + i)) * 256 + j] = red[tid][0] + red[tid][1] + b3[0];
    }
}

// ---------------------------------------------------------------------------
extern "C" void kernel_launch(void* const* d_in, const int* in_sizes, int n_in,
                              void* d_out, int out_size, void* d_ws, size_t ws_size,
                              hipStream_t stream)
{
    const float* emb   = (const float*)d_in[0];
    const float* bp    = (const float*)d_in[1];
    const float* ew1   = (const float*)d_in[3];
    const float* eb1   = (const float*)d_in[4];
    const float* ew2   = (const float*)d_in[5];
    const float* eb2   = (const float*)d_in[6];
    const float* wself = (const float*)d_in[7];
    const float* bself = (const float*)d_in[8];
    const float* wedge = (const float*)d_in[9];
    const float* bedge = (const float*)d_in[10];
    const float* lng   = (const float*)d_in[11];
    const float* lnb   = (const float*)d_in[12];
    const float* mw1   = (const float*)d_in[13];
    const float* mb1   = (const float*)d_in[14];
    const float* mw2   = (const float*)d_in[15];
    const float* mb2   = (const float*)d_in[16];
    const float* mw3   = (const float*)d_in[17];
    const float* mb3   = (const float*)d_in[18];
    float* out = (float*)d_out;

    float* ws = (float*)d_ws;
    float* h1 = ws;               // 524288  (enc hidden)
    float* xe = h1 + 524288;      // 262144  (enc out)
    float* sf = xe + 262144;      // 262144
    float* eg = sf + 262144;      // 262144
    float* x0 = eg + 262144;      // 262144  (pre-LN layer outs)
    float* x1 = x0 + 262144;
    float* x2 = x1 + 262144;
    float* hi = x2 + 262144;
    float* hj = hi + 262144;      // floats so far: 2,621,440
    short* w2th = (short*)(hj + 262144);   // 32768 shorts
    short* w2tl = w2th + 32768;            // 32768 shorts
    float* ps0  = (float*)(w2tl + 32768);  // 3 x [4][1024][2] = 3 x 8192 floats
    float* ps1  = ps0 + 8192;
    float* ps2  = ps1 + 8192;

    float* xs[3]  = {x0, x1, x2};
    float* pss[3] = {ps0, ps1, ps2};
    dim3 blk(256);

    splitw2<<<dim3(128), blk, 0, stream>>>(mw2, w2th, w2tl);

    // FeatureEncoder
    gemm_f32<true, false><<<dim3(8, 32), blk, 0, stream>>>(emb, ew1, eb1, h1,
        nullptr, nullptr, nullptr, nullptr, nullptr, nullptr, 1024, 512, 640, 0);
    gemm_f32<false, false><<<dim3(4, 32), blk, 0, stream>>>(h1, ew2, eb2, xe,
        nullptr, nullptr, nullptr, nullptr, nullptr, nullptr, 1024, 256, 512, 0);

    // GCN layers: dual self/edge (LN-on-load for l>=1), bmm+relu+stats
    for (int l = 0; l < 3; ++l) {
        const float* Ain = (l == 0) ? xe : xs[l - 1];
        if (l == 0)
            gemm_f32<false, false><<<dim3(8, 32), blk, 0, stream>>>(Ain,
                wself, bself, sf, wedge, bedge, eg,
                nullptr, nullptr, nullptr, 1024, 256, 256, 4);
        else
            gemm_f32<false, true><<<dim3(8, 32), blk, 0, stream>>>(Ain,
                wself + l * 65536, bself + l * 256, sf,
                wedge + l * 65536, bedge + l * 256, eg,
                pss[l - 1], lng + (l - 1) * 256, lnb + (l - 1) * 256,
                1024, 256, 256, 4);
        bmm_fuse<<<dim3(4, 8, 4), blk, 0, stream>>>(bp, eg, sf, xs[l], pss[l]);
    }

    // hi / hj partial products (dual, LN(x2) applied on A-load)
    gemm_f32<false, true><<<dim3(8, 32), blk, 0, stream>>>(x2,
        mw1, nullptr, hi, mw1 + 65536, nullptr, hj,
        ps2, lng + 512, lnb + 512, 1024, 256, 256, 4);

    // Fused pairwise MFMA scorer
    pairwise3<<<dim3(4, 128, 4), blk, 0, stream>>>(hi, hj, bp,
        mw1 + 131072, mb1, w2th, w2tl, mb2, mw3, mb3, out);
}

// Round 7
// 303.049 us; speedup vs baseline: 3.6169x; 1.0414x over previous
//
#include <hip/hip_runtime.h>

typedef __attribute__((ext_vector_type(8))) short short8;
typedef __attribute__((ext_vector_type(4))) float f32x4;
typedef __attribute__((ext_vector_type(4))) unsigned uint4v;

__device__ __forceinline__ void gload_lds16(const void* g, void* l) {
    __builtin_amdgcn_global_load_lds(
        (const __attribute__((address_space(1))) unsigned*)g,
        (__attribute__((address_space(3))) unsigned*)l, 16, 0, 0);
}
#define MFMA16(a, b, c) __builtin_amdgcn_mfma_f32_16x16x32_bf16((a), (b), (c), 0, 0, 0)

// ---------------------------------------------------------------------------
// fp32 GEMM: BM=32 BN=32 BK=32, 256 thr, 1x4 microtile. Dual-B via nxHalf.
// Optional LN-on-A-load (stats from ps[4][1024][2]).
// Optional fused w2-split side-job on blocks with blockIdx.y >= 32.
// ---------------------------------------------------------------------------
template<bool RELU, bool LNA, bool SPLITW2>
__global__ __launch_bounds__(256)
void gemm_s(const float* __restrict__ A,
            const float* __restrict__ B0, const float* __restrict__ bias0,
            float* __restrict__ C0,
            const float* __restrict__ B1, const float* __restrict__ bias1,
            float* __restrict__ C1,
            const float* __restrict__ ps, const float* __restrict__ lg,
            const float* __restrict__ lb,
            int M, int N, int K, int nxHalf,
            const float* __restrict__ w2, short* __restrict__ w2th,
            short* __restrict__ w2tl)
{
    if (SPLITW2 && blockIdx.y >= 32) {
        int e = ((blockIdx.y - 32) * gridDim.x + blockIdx.x) * 256 + threadIdx.x;
        if (e < 32768) {
            int k = e >> 7, n = e & 127;
            float x = w2[e];
            unsigned hu = __float_as_uint(x) & 0xFFFF0000u;
            w2th[n * 256 + k] = (short)(hu >> 16);
            w2tl[n * 256 + k] = (short)(__float_as_uint(x - __uint_as_float(hu)) >> 16);
        }
        return;
    }
    int bx = blockIdx.x;
    const float* B = B0; const float* bias = bias0; float* C = C0;
    if (nxHalf && bx >= nxHalf) { bx -= nxHalf; B = B1; bias = bias1; C = C1; }
    const int m0 = blockIdx.y * 32, n0 = bx * 32;
    const int tid = threadIdx.x;
    const int tx = tid & 7, ty = tid >> 3;

    __shared__ __align__(16) float As[32 * 36];
    __shared__ __align__(16) float Bs[32 * 36];
    __shared__ float mus[32], rss[32];

    if (LNA) {
        if (tid < 32) {
            int m = m0 + tid;
            float s  = ps[m * 2]            + ps[2048 + m * 2]
                     + ps[4096 + m * 2]     + ps[6144 + m * 2];
            float s2 = ps[m * 2 + 1]        + ps[2048 + m * 2 + 1]
                     + ps[4096 + m * 2 + 1] + ps[6144 + m * 2 + 1];
            float mu  = s * (1.f / 256.f);
            float var = s2 * (1.f / 256.f) - mu * mu;
            mus[tid] = mu;
            rss[tid] = rsqrtf(var + 1e-5f);
        }
        __syncthreads();
    }

    float acc[4] = {};
    for (int k0 = 0; k0 < K; k0 += 32) {
        {   // A tile (transposed to As[k][m]), optional LN
            int row = ty, kq = tx << 2;
            float4 v = *(const float4*)&A[(long)(m0 + row) * K + k0 + kq];
            if (LNA) {
                float4 gv = *(const float4*)&lg[k0 + kq];
                float4 bv = *(const float4*)&lb[k0 + kq];
                float mu = mus[row], rs = rss[row];
                v.x = (v.x - mu) * rs * gv.x + bv.x;
                v.y = (v.y - mu) * rs * gv.y + bv.y;
                v.z = (v.z - mu) * rs * gv.z + bv.z;
                v.w = (v.w - mu) * rs * gv.w + bv.w;
            }
            As[(kq + 0) * 36 + row] = v.x; As[(kq + 1) * 36 + row] = v.y;
            As[(kq + 2) * 36 + row] = v.z; As[(kq + 3) * 36 + row] = v.w;
        }
        *(float4*)&Bs[ty * 36 + tx * 4] =
            *(const float4*)&B[(long)(k0 + ty) * N + n0 + tx * 4];
        __syncthreads();
#pragma unroll
        for (int k = 0; k < 32; ++k) {
            float a = As[k * 36 + ty];
            float4 b4 = *(const float4*)&Bs[k * 36 + tx * 4];
            acc[0] += a * b4.x; acc[1] += a * b4.y;
            acc[2] += a * b4.z; acc[3] += a * b4.w;
        }
        __syncthreads();
    }

    int m = m0 + ty;
#pragma unroll
    for (int j = 0; j < 4; ++j) {
        int n = n0 + tx * 4 + j;
        float v = acc[j];
        if (bias) v += bias[n];
        if (RELU) v = fmaxf(v, 0.f);
        C[(long)m * N + n] = v;
    }
}

// ---------------------------------------------------------------------------
// bmm + fused x = relu(sf + bp@eg) + per-row partial LN stats (no atomics).
// Grid (4 n-tiles, 8 m-tiles, 4 batch). ps layout: [jb][1024][2]. (R5-proven)
// ---------------------------------------------------------------------------
__global__ __launch_bounds__(256)
void bmm_fuse(const float* __restrict__ bp, const float* __restrict__ eg,
              const float* __restrict__ sf, float* __restrict__ x,
              float* __restrict__ ps)
{
    const int b = blockIdx.z, jb = blockIdx.x;
    const int m0 = blockIdx.y * 32, n0 = jb * 64;
    const float* A = bp + b * 65536;
    const float* B = eg + b * 65536;
    const int tid = threadIdx.x;
    const int tx = tid & 15, ty = tid >> 4;

    __shared__ __align__(16) float As[32 * 36];
    __shared__ __align__(16) float Bs[32 * 68];

    float acc[2][4] = {};
    for (int k0 = 0; k0 < 256; k0 += 32) {
        {
            int row = tid >> 3, kq = (tid & 7) << 2;
            float4 v = *(const float4*)&A[(long)(m0 + row) * 256 + k0 + kq];
            As[(kq + 0) * 36 + row] = v.x; As[(kq + 1) * 36 + row] = v.y;
            As[(kq + 2) * 36 + row] = v.z; As[(kq + 3) * 36 + row] = v.w;
        }
#pragma unroll
        for (int q = 0; q < 2; ++q) {
            int f = tid * 2 + q;
            int kk = f >> 4, nn = (f & 15) << 2;
            *(float4*)&Bs[kk * 68 + nn] = *(const float4*)&B[(long)(k0 + kk) * 256 + n0 + nn];
        }
        __syncthreads();
#pragma unroll
        for (int k = 0; k < 32; ++k) {
            float2 a2 = *(const float2*)&As[k * 36 + ty * 2];
            float4 b4 = *(const float4*)&Bs[k * 68 + tx * 4];
            acc[0][0] += a2.x * b4.x; acc[0][1] += a2.x * b4.y;
            acc[0][2] += a2.x * b4.z; acc[0][3] += a2.x * b4.w;
            acc[1][0] += a2.y * b4.x; acc[1][1] += a2.y * b4.y;
            acc[1][2] += a2.y * b4.z; acc[1][3] += a2.y * b4.w;
        }
        __syncthreads();
    }

#pragma unroll
    for (int i = 0; i < 2; ++i) {
        int gm = b * 256 + m0 + ty * 2 + i;
        float s = 0.f, s2 = 0.f;
#pragma unroll
        for (int j = 0; j < 4; ++j) {
            int n = n0 + tx * 4 + j;
            float v = fmaxf(acc[i][j] + sf[(long)gm * 256 + n], 0.f);
            x[(long)gm * 256 + n] = v;
            s += v; s2 += v * v;
        }
        s  += __shfl_xor(s, 1, 64);  s2 += __shfl_xor(s2, 1, 64);
        s  += __shfl_xor(s, 2, 64);  s2 += __shfl_xor(s2, 2, 64);
        s  += __shfl_xor(s, 4, 64);  s2 += __shfl_xor(s2, 4, 64);
        s  += __shfl_xor(s, 8, 64);  s2 += __shfl_xor(s2, 8, 64);
        if (tx == 0) {
            ps[jb * 2048 + gm * 2]     = s;
            ps[jb * 2048 + gm * 2 + 1] = s2;
        }
    }
}

// ---------------------------------------------------------------------------
// Pairwise scorer v4: all-b128 LDS traffic (even-banked), double-buffered P,
// ONE barrier per k-tile, MFMA bf16 3-pass hi/lo.
// Block: 128 pairs (2 i x 64 j) x N=128, 4 waves (2 pair-halves x 2 N-halves).
// P layout: [row 0..127][32 k] shorts, 64B rows, byte ^= (row&7)<<4;
//   every access (store & fragment read) is an aligned b128 at
//   (row*64 + oct*16) ^ swz  -> words spread evenly over all 32 banks.
// ---------------------------------------------------------------------------
#define STAGE_HJ(T, BUF)                                                        \
    {                                                                           \
        int row = tid >> 3, s = tid & 7;                                        \
        gload_lds16(&hja[((long)(b * 256 + j0 + row)) * 256 + (T) * 32          \
                         + ((s ^ (row & 7)) << 2)],                             \
                    (char*)&hjs[BUF][0] + tid * 16);                            \
        int row2 = row + 32;                                                    \
        gload_lds16(&hja[((long)(b * 256 + j0 + row2)) * 256 + (T) * 32         \
                         + ((s ^ (row2 & 7)) << 2)],                            \
                    (char*)&hjs[BUF][0] + 4096 + tid * 16);                     \
    }

// thread -> row p = tid>>1 (0..127), octets {o0, o0+1} with o0 = (tid&1)*2.
// Each octet: read 8 hj floats (2 b128, slot-swizzled), compute 8 P values,
// split hi/lo, ONE b128 store each into Ph/Pl.
#define BUILD_P(KT, BUF)                                                        \
    {                                                                           \
        const char* hbase = (const char*)&hjs[BUF][0] + jj * 128;               \
        char* phc = (char*)&Ph[BUF][0];                                         \
        char* plc = (char*)&Pl[BUF][0];                                         \
        const int swz = (p & 7) << 4;                                           \
        _Pragma("unroll")                                                       \
        for (int q = 0; q < 2; ++q) {                                           \
            const int oct = o0 + q;                                             \
            float4 hv0 = *(const float4*)(hbase + (((oct * 2)     ^ (jj & 7)) << 4)); \
            float4 hv1 = *(const float4*)(hbase + (((oct * 2 + 1) ^ (jj & 7)) << 4)); \
            float4 iv0 = *(const float4*)&hib[ii][(KT) * 32 + oct * 8];         \
            float4 iv1 = *(const float4*)&hib[ii][(KT) * 32 + oct * 8 + 4];     \
            float4 cv0 = *(const float4*)&csv[(KT) * 32 + oct * 8];             \
            float4 cv1 = *(const float4*)&csv[(KT) * 32 + oct * 8 + 4];         \
            float x0 = fmaxf(fmaf(bpw, cv0.x, iv0.x) + hv0.x, 0.f);             \
            float x1 = fmaxf(fmaf(bpw, cv0.y, iv0.y) + hv0.y, 0.f);             \
            float x2 = fmaxf(fmaf(bpw, cv0.z, iv0.z) + hv0.z, 0.f);             \
            float x3 = fmaxf(fmaf(bpw, cv0.w, iv0.w) + hv0.w, 0.f);             \
            float x4 = fmaxf(fmaf(bpw, cv1.x, iv1.x) + hv1.x, 0.f);             \
            float x5 = fmaxf(fmaf(bpw, cv1.y, iv1.y) + hv1.y, 0.f);             \
            float x6 = fmaxf(fmaf(bpw, cv1.z, iv1.z) + hv1.z, 0.f);             \
            float x7 = fmaxf(fmaf(bpw, cv1.w, iv1.w) + hv1.w, 0.f);             \
            unsigned h0 = __float_as_uint(x0) & 0xFFFF0000u;                    \
            unsigned h1 = __float_as_uint(x1) & 0xFFFF0000u;                    \
            unsigned h2 = __float_as_uint(x2) & 0xFFFF0000u;                    \
            unsigned h3 = __float_as_uint(x3) & 0xFFFF0000u;                    \
            unsigned h4 = __float_as_uint(x4) & 0xFFFF0000u;                    \
            unsigned h5 = __float_as_uint(x5) & 0xFFFF0000u;                    \
            unsigned h6 = __float_as_uint(x6) & 0xFFFF0000u;                    \
            unsigned h7 = __float_as_uint(x7) & 0xFFFF0000u;                    \
            uint4v hv_, lv_;                                                    \
            hv_[0] = (h0 >> 16) | h1;                                           \
            hv_[1] = (h2 >> 16) | h3;                                           \
            hv_[2] = (h4 >> 16) | h5;                                           \
            hv_[3] = (h6 >> 16) | h7;                                           \
            lv_[0] = (__float_as_uint(x0 - __uint_as_float(h0)) >> 16)          \
                   | (__float_as_uint(x1 - __uint_as_float(h1)) & 0xFFFF0000u); \
            lv_[1] = (__float_as_uint(x2 - __uint_as_float(h2)) >> 16)          \
                   | (__float_as_uint(x3 - __uint_as_float(h3)) & 0xFFFF0000u); \
            lv_[2] = (__float_as_uint(x4 - __uint_as_float(h4)) >> 16)          \
                   | (__float_as_uint(x5 - __uint_as_float(h5)) & 0xFFFF0000u); \
            lv_[3] = (__float_as_uint(x6 - __uint_as_float(h6)) >> 16)          \
                   | (__float_as_uint(x7 - __uint_as_float(h7)) & 0xFFFF0000u); \
            int sbyte = p * 64 + oct * 16;                                      \
            *(uint4v*)(phc + (sbyte ^ swz)) = hv_;                              \
            *(uint4v*)(plc + (sbyte ^ swz)) = lv_;                              \
        }                                                                       \
    }

__global__ __launch_bounds__(256, 3)
void pairwise4(const float* __restrict__ hia, const float* __restrict__ hja,
               const float* __restrict__ bpm,
               const float* __restrict__ c, const float* __restrict__ b1,
               const short* __restrict__ w2th, const short* __restrict__ w2tl,
               const float* __restrict__ b2, const float* __restrict__ w3,
               const float* __restrict__ b3, float* __restrict__ out)
{
    const int b = blockIdx.z, ib0 = blockIdx.y * 2, j0 = blockIdx.x * 64;
    const int tid = threadIdx.x, l = tid & 63, wid = tid >> 6;
    const int wm0 = (wid & 1) * 64, wn0 = (wid >> 1) * 64;
    const int g = l >> 4, ln = l & 15;
    const int p = tid >> 1, jj = p & 63, ii = p >> 6, o0 = (tid & 1) * 2;

    __shared__ __align__(16) short Ph[2][4096];
    __shared__ __align__(16) short Pl[2][4096];
    __shared__ __align__(16) float hjs[2][2048];   // 128B rows, slot-swizzled
    __shared__ __align__(16) float hib[2][256];    // hi row + b1
    __shared__ __align__(16) float csv[256];
    __shared__ float bpv[128];
    __shared__ float red[128][2];

    if (tid < 128)
        bpv[tid] = bpm[((long)(b * 256 + ib0 + (tid >> 6))) * 256 + j0 + (tid & 63)];
    {
        int i2 = tid >> 7, kk = (tid & 127) * 2;
        float2 hv = *(const float2*)&hia[((long)(b * 256 + ib0 + i2)) * 256 + kk];
        float2 bv = *(const float2*)&b1[kk];
        hib[i2][kk] = hv.x + bv.x; hib[i2][kk + 1] = hv.y + bv.y;
    }
    if (tid < 64) *(float4*)&csv[tid * 4] = *(const float4*)&c[tid * 4];

    STAGE_HJ(0, 0);
    __syncthreads();                 // hjs0 + persistent staging visible
    const float bpw = bpv[p];
    STAGE_HJ(1, 1);
    BUILD_P(0, 0);
    __syncthreads();                 // P0 visible, hjs1 drained

    f32x4 acc[4][4] = {};

#pragma unroll
    for (int kt = 0; kt < 8; ++kt) {
        const int cur = kt & 1;
        if (kt < 6) STAGE_HJ(kt + 2, cur);
        // B(t) fragments (global, L2-hot) — issued early
        short8 bh[4], bl[4];
#pragma unroll
        for (int nf = 0; nf < 4; ++nf) {
            int col = wn0 + nf * 16 + ln;
            long bo = (long)col * 256 + kt * 32 + g * 8;
            bh[nf] = *(const short8*)(w2th + bo);
            bl[nf] = *(const short8*)(w2tl + bo);
        }
        // build P(t+1) while B loads are in flight
        if (kt < 7) BUILD_P(kt + 1, cur ^ 1);
        // A(t) fragments from P[cur]
        short8 ah[4], al[4];
#pragma unroll
        for (int mf = 0; mf < 4; ++mf) {
            int row = wm0 + mf * 16 + ln;
            int off = (row * 64 + g * 16) ^ ((row & 7) << 4);
            ah[mf] = *(const short8*)((const char*)&Ph[cur][0] + off);
            al[mf] = *(const short8*)((const char*)&Pl[cur][0] + off);
        }
#pragma unroll
        for (int mf = 0; mf < 4; ++mf)
#pragma unroll
            for (int nf = 0; nf < 4; ++nf) {
                acc[mf][nf] = MFMA16(ah[mf], bh[nf], acc[mf][nf]);
                acc[mf][nf] = MFMA16(ah[mf], bl[nf], acc[mf][nf]);
                acc[mf][nf] = MFMA16(al[mf], bh[nf], acc[mf][nf]);
            }
        __syncthreads();
    }

    // epilogue: relu(+b2) dot w3, 16-lane shfl reduce, cross-wave via LDS
    float b2v[4], w3v[4];
#pragma unroll
    for (int nf = 0; nf < 4; ++nf) {
        int col = wn0 + nf * 16 + ln;
        b2v[nf] = b2[col];
        w3v[nf] = w3[col];
    }
#pragma unroll
    for (int mf = 0; mf < 4; ++mf) {
#pragma unroll
        for (int r = 0; r < 4; ++r) {
            float s = 0.f;
#pragma unroll
            for (int nf = 0; nf < 4; ++nf)
                s += fmaxf(acc[mf][nf][r] + b2v[nf], 0.f) * w3v[nf];
            s += __shfl_xor(s, 1, 64);
            s += __shfl_xor(s, 2, 64);
            s += __shfl_xor(s, 4, 64);
            s += __shfl_xor(s, 8, 64);
            if (ln == 0)
                red[wm0 + mf * 16 + g * 4 + r][wid >> 1] = s;
        }
    }
    __syncthreads();
    if (tid < 128) {
        int i = ib0 + (tid >> 6), j = j0 + (tid & 63);
        out[((long)(b * 256 + i)) * 256 + j] = red[tid][0] + red[tid][1] + b3[0];
    }
}

// ---------------------------------------------------------------------------
extern "C" void kernel_launch(void* const* d_in, const int* in_sizes, int n_in,
                              void* d_out, int out_size, void* d_ws, size_t ws_size,
                              hipStream_t stream)
{
    const float* emb   = (const float*)d_in[0];
    const float* bp    = (const float*)d_in[1];
    const float* ew1   = (const float*)d_in[3];
    const float* eb1   = (const float*)d_in[4];
    const float* ew2   = (const float*)d_in[5];
    const float* eb2   = (const float*)d_in[6];
    const float* wself = (const float*)d_in[7];
    const float* bself = (const float*)d_in[8];
    const float* wedge = (const float*)d_in[9];
    const float* bedge = (const float*)d_in[10];
    const float* lng   = (const float*)d_in[11];
    const float* lnb   = (const float*)d_in[12];
    const float* mw1   = (const float*)d_in[13];
    const float* mb1   = (const float*)d_in[14];
    const float* mw2   = (const float*)d_in[15];
    const float* mb2   = (const float*)d_in[16];
    const float* mw3   = (const float*)d_in[17];
    const float* mb3   = (const float*)d_in[18];
    float* out = (float*)d_out;

    float* ws = (float*)d_ws;
    float* h1 = ws;               // 524288  (enc hidden)
    float* xe = h1 + 524288;      // 262144  (enc out)
    float* sf = xe + 262144;      // 262144
    float* eg = sf + 262144;      // 262144
    float* x0 = eg + 262144;      // 262144  (pre-LN layer outs)
    float* x1 = x0 + 262144;
    float* x2 = x1 + 262144;
    float* hi = x2 + 262144;
    float* hj = hi + 262144;
    short* w2th = (short*)(hj + 262144);   // 32768 shorts
    short* w2tl = w2th + 32768;            // 32768 shorts
    float* ps0  = (float*)(w2tl + 32768);  // 3 x [4][1024][2]
    float* ps1  = ps0 + 8192;
    float* ps2  = ps1 + 8192;

    float* xs[3]  = {x0, x1, x2};
    float* pss[3] = {ps0, ps1, ps2};
    dim3 blk(256);

    // FeatureEncoder  (enc1 grid-sliced with the w2 transpose+split side-job)
    gemm_s<true, false, true><<<dim3(16, 40), blk, 0, stream>>>(emb, ew1, eb1, h1,
        nullptr, nullptr, nullptr, nullptr, nullptr, nullptr,
        1024, 512, 640, 0, mw2, w2th, w2tl);
    gemm_s<false, false, false><<<dim3(8, 32), blk, 0, stream>>>(h1, ew2, eb2, xe,
        nullptr, nullptr, nullptr, nullptr, nullptr, nullptr,
        1024, 256, 512, 0, nullptr, nullptr, nullptr);

    // GCN layers: dual self/edge (LN-on-load for l>=1), bmm+relu+stats
    for (int lyr = 0; lyr < 3; ++lyr) {
        const float* Ain = (lyr == 0) ? xe : xs[lyr - 1];
        if (lyr == 0)
            gemm_s<false, false, false><<<dim3(16, 32), blk, 0, stream>>>(Ain,
                wself, bself, sf, wedge, bedge, eg,
                nullptr, nullptr, nullptr, 1024, 256, 256, 8,
                nullptr, nullptr, nullptr);
        else
            gemm_s<false, true, false><<<dim3(16, 32), blk, 0, stream>>>(Ain,
                wself + lyr * 65536, bself + lyr * 256, sf,
                wedge + lyr * 65536, bedge + lyr * 256, eg,
                pss[lyr - 1], lng + (lyr - 1) * 256, lnb + (lyr - 1) * 256,
                1024, 256, 256, 8, nullptr, nullptr, nullptr);
        bmm_fuse<<<dim3(4, 8, 4), blk, 0, stream>>>(bp, eg, sf, xs[lyr], pss[lyr]);
    }

    // hi / hj partial products (dual, LN(x2) applied on A-load)
    gemm_s<false, true, false><<<dim3(16, 32), blk, 0, stream>>>(x2,
        mw1, nullptr, hi, mw1 + 65536, nullptr, hj,
        ps2, lng + 512, lnb + 512, 1024, 256, 256, 8,
        nullptr, nullptr, nullptr);

    // Fused pairwise MFMA scorer
    pairwise4<<<dim3(4, 128, 4), blk, 0, stream>>>(hi, hj, bp,
        mw1 + 131072, mb1, w2th, w2tl, mb2, mw3, mb3, out);
}